// Round 4
// baseline (82.939 us; speedup 1.0000x reference)
//
#include <hip/hip_runtime.h>
#include <math.h>

#define BN 1024   // batch
#define CN 512    // clusters
#define DN 256    // dims
#define TM 128
#define TN 64
#define KZ 32
#define NZ (DN / KZ)   // 8 K-chunks

// ws layout (floats): xs[BN*DN] | r[BN] | q[CN] | pdot[NZ*BN*CN]
#define XS_OFF 0
#define R_OFF  (BN * DN)
#define Q_OFF  (R_OFF + BN)
#define PD_OFF (Q_OFF + CN)   // 263680, 16B-aligned

// ---------------------------------------------------------------------------
// prep: a_d = attn_d / sum(attn);  xs[b,d] = a_d * x[b,d];
//       r[b] = sum_d a_d x^2;  q[c] = sum_d a_d w^2.
// grid BN+CN blocks x 256 threads (1 row each, attn sum redundant per block).
// ---------------------------------------------------------------------------
__launch_bounds__(256, 4)
__global__ void prep_kernel(const float* __restrict__ inp, const float* __restrict__ wd,
                            const float* __restrict__ attn, float* __restrict__ ws) {
    __shared__ float red[4];
    float* xs = ws + XS_OFF;
    float* r  = ws + R_OFF;
    float* q  = ws + Q_OFF;

    const int tid  = threadIdx.x;          // == d, 256 threads = DN
    const int lane = tid & 63;
    const int blk  = blockIdx.x;

    float av = attn[tid];
    float s = av;
    #pragma unroll
    for (int off = 32; off > 0; off >>= 1) s += __shfl_xor(s, off);
    if (lane == 0) red[tid >> 6] = s;
    __syncthreads();
    const float a = av / (red[0] + red[1] + red[2] + red[3]);

    float c;
    if (blk < BN) {
        const float x = inp[blk * DN + tid];
        xs[blk * DN + tid] = a * x;
        c = a * x * x;
    } else {
        const float w = wd[(blk - BN) * DN + tid];
        c = a * w * w;
    }
    #pragma unroll
    for (int off = 32; off > 0; off >>= 1) c += __shfl_xor(c, off);
    __syncthreads();                       // red[] reuse
    if (lane == 0) red[tid >> 6] = c;
    __syncthreads();
    if (tid == 0) {
        const float tot = red[0] + red[1] + red[2] + red[3];
        if (blk < BN) r[blk] = tot; else q[blk - BN] = tot;
    }
}

// ---------------------------------------------------------------------------
// dist: pdot[z][b][c] = sum_{k in chunk z} xs[b,k] * wd[c,k]   (pure GEMM)
// grid (8, 8, 8) = 512 blocks = 2/CU, 256 threads, 8x4 outputs/thread.
// LDS k-major [row][KZ], float4 groups XOR-swizzled by (row>>3)&7 so the
// per-fragment ds_read_b128 spread across all 8 bank-quads (<=2-way).
// ---------------------------------------------------------------------------
__launch_bounds__(256, 2)
__global__ void dist_kernel(const float* __restrict__ ws_ro, const float* __restrict__ wd,
                            float* __restrict__ ws) {
    __shared__ __align__(16) float aT[TM * KZ];   // 16 KB
    __shared__ __align__(16) float bT[TN * KZ];   //  8 KB

    const float* xs = ws_ro + XS_OFF;
    float* pdot = ws + PD_OFF + (size_t)blockIdx.z * BN * CN;

    const int tid = threadIdx.x;
    const int m0 = blockIdx.x * TM;
    const int n0 = blockIdx.y * TN;
    const int k0 = blockIdx.z * KZ;

    // ---- stage A: 128 rows x 8 float4; 4 float4 per thread ----
    {
        const int row = tid >> 1;              // 0..127
        const int g0  = (tid & 1) * 4;         // 0 or 4
        const int sw  = (row >> 3) & 7;
        const float* src = &xs[(m0 + row) * DN + k0 + 4 * g0];
        float4* dst = (float4*)&aT[row * KZ];
        #pragma unroll
        for (int j = 0; j < 4; ++j)
            dst[(g0 + j) ^ sw] = *(const float4*)&src[4 * j];
    }
    // ---- stage B: 64 rows x 8 float4; 2 float4 per thread ----
    {
        const int row = tid >> 2;              // 0..63
        const int g0  = (tid & 3) * 2;         // 0,2,4,6
        const int sw  = (row >> 3) & 7;
        const float* src = &wd[(n0 + row) * DN + k0 + 4 * g0];
        float4* dst = (float4*)&bT[row * KZ];
        #pragma unroll
        for (int j = 0; j < 2; ++j)
            dst[(g0 + j) ^ sw] = *(const float4*)&src[4 * j];
    }
    __syncthreads();

    const int tr = tid & 15;                   // A row-group: rows 8*tr..8*tr+7
    const int tc = tid >> 4;                   // B row-group: rows 4*tc..4*tc+3
    const int swa = tr & 7;                    // == (row>>3)&7 for rows 8tr+i
    const int swb = (tc >> 1) & 7;             // == (row>>3)&7 for rows 4tc+j
    float acc[8][4] = {};

    #pragma unroll
    for (int k4 = 0; k4 < KZ / 4; ++k4) {
        float4 av[8], bv[4];
        #pragma unroll
        for (int i = 0; i < 8; ++i)
            av[i] = ((const float4*)&aT[(8 * tr + i) * KZ])[k4 ^ swa];
        #pragma unroll
        for (int j = 0; j < 4; ++j)
            bv[j] = ((const float4*)&bT[(4 * tc + j) * KZ])[k4 ^ swb];
        #pragma unroll
        for (int i = 0; i < 8; ++i)
            #pragma unroll
            for (int j = 0; j < 4; ++j) {
                float t = fmaf(av[i].x, bv[j].x, acc[i][j]);
                t = fmaf(av[i].y, bv[j].y, t);
                t = fmaf(av[i].z, bv[j].z, t);
                acc[i][j] = fmaf(av[i].w, bv[j].w, t);
            }
    }

    #pragma unroll
    for (int i = 0; i < 8; ++i) {
        float4 o = {acc[i][0], acc[i][1], acc[i][2], acc[i][3]};
        *(float4*)&pdot[(m0 + 8 * tr + i) * CN + n0 + 4 * tc] = o;
    }
}

// ---------------------------------------------------------------------------
// finish: wdist = r_b + q_c - 2*dot; t = sqrt(wdist); double softmax; readout.
// One wave per batch row, 8 clusters/lane. grid 256 x 256.
// ---------------------------------------------------------------------------
#define NEG_INF_F (-1e30f)

__device__ __forceinline__ float waveMax(float v) {
    #pragma unroll
    for (int off = 32; off > 0; off >>= 1) v = fmaxf(v, __shfl_xor(v, off));
    return v;
}
__device__ __forceinline__ float waveSum(float v) {
    #pragma unroll
    for (int off = 32; off > 0; off >>= 1) v += __shfl_xor(v, off);
    return v;
}

__launch_bounds__(256, 2)
__global__ void finish_kernel(const float* __restrict__ ws, const int* __restrict__ mask,
                              const float* __restrict__ w_assoc, float* __restrict__ y) {
    const float* r    = ws + R_OFF;
    const float* q    = ws + Q_OFF;
    const float* pdot = ws + PD_OFF;

    const int tid  = threadIdx.x;
    const int lane = tid & 63;
    const int b    = blockIdx.x * 4 + (tid >> 6);
    const int cb   = lane * 8;                 // 8 consecutive clusters per lane

    // combine K-chunk dot partials
    float dot[8] = {};
    #pragma unroll
    for (int z = 0; z < NZ; ++z) {
        const float* pz = &pdot[(size_t)z * BN * CN + b * CN + cb];
        #pragma unroll
        for (int s4 = 0; s4 < 2; ++s4) {
            const float4 v = *(const float4*)&pz[4 * s4];
            dot[4 * s4 + 0] += v.x; dot[4 * s4 + 1] += v.y;
            dot[4 * s4 + 2] += v.z; dot[4 * s4 + 3] += v.w;
        }
    }
    const float rb = r[b];
    const float4 q0 = *(const float4*)&q[cb];
    const float4 q1 = *(const float4*)&q[cb + 4];
    const float qv[8] = {q0.x, q0.y, q0.z, q0.w, q1.x, q1.y, q1.z, q1.w};

    float t[8];
    #pragma unroll
    for (int j = 0; j < 8; ++j)
        t[j] = sqrtf(fmaxf(rb + qv[j] - 2.0f * dot[j], 0.0f));

    const int4 mm0 = *(const int4*)&mask[cb];
    const int4 mm1 = *(const int4*)&mask[cb + 4];
    const bool rec[8] = {mm0.x > 0, mm0.y > 0, mm0.z > 0, mm0.w > 0,
                         mm1.x > 0, mm1.y > 0, mm1.z > 0, mm1.w > 0};

    // softmax #1: logits -3*t (BETA*log H / TEMP_COMP)
    float l1[8], lmax = NEG_INF_F;
    #pragma unroll
    for (int j = 0; j < 8; ++j) { l1[j] = rec[j] ? (-3.0f * t[j]) : NEG_INF_F; lmax = fmaxf(lmax, l1[j]); }
    const float mx1 = waveMax(lmax);
    float e1[8], lsum = 0.f;
    #pragma unroll
    for (int j = 0; j < 8; ++j) { e1[j] = rec[j] ? expf(l1[j] - mx1) : 0.f; lsum += e1[j]; }
    const float inv_s1 = 1.0f / waveSum(lsum);

    float competed[8];
    #pragma unroll
    for (int j = 0; j < 8; ++j) competed[j] = e1[j] * inv_s1 * expf(-t[j]);

    // softmax #2: logits competed / 0.1
    float l2[8]; lmax = NEG_INF_F;
    #pragma unroll
    for (int j = 0; j < 8; ++j) { l2[j] = rec[j] ? (competed[j] * 10.0f) : NEG_INF_F; lmax = fmaxf(lmax, l2[j]); }
    const float mx2 = waveMax(lmax);
    float e2[8]; lsum = 0.f;
    #pragma unroll
    for (int j = 0; j < 8; ++j) { e2[j] = rec[j] ? expf(l2[j] - mx2) : 0.f; lsum += e2[j]; }
    const float inv_s2 = 1.0f / waveSum(lsum);

    // readout y = 1.5 * (softwta @ w_assoc)
    float y0 = 0.f, y1 = 0.f;
    #pragma unroll
    for (int p = 0; p < 4; ++p) {
        const float4 wa = *(const float4*)&w_assoc[2 * cb + 4 * p];   // clusters 2p, 2p+1
        const float sw0 = e2[2 * p + 0] * inv_s2 * competed[2 * p + 0];
        const float sw1 = e2[2 * p + 1] * inv_s2 * competed[2 * p + 1];
        y0 = fmaf(sw0, wa.x, y0); y1 = fmaf(sw0, wa.y, y1);
        y0 = fmaf(sw1, wa.z, y0); y1 = fmaf(sw1, wa.w, y1);
    }
    y0 = waveSum(y0);
    y1 = waveSum(y1);
    if (lane == 0) {
        float2 o = {1.5f * y0, 1.5f * y1};
        *(float2*)&y[b * 2] = o;
    }
}

extern "C" void kernel_launch(void* const* d_in, const int* in_sizes, int n_in,
                              void* d_out, int out_size, void* d_ws, size_t ws_size,
                              hipStream_t stream) {
    const float* inp     = (const float*)d_in[0];  // [B, D]
    const float* w_dist  = (const float*)d_in[1];  // [C, D]
    const float* attn    = (const float*)d_in[2];  // [D]
    const float* w_assoc = (const float*)d_in[3];  // [C, 2]
    const int*   mask    = (const int*)d_in[4];    // [C]
    float* out = (float*)d_out;                    // [B, 2]
    float* ws  = (float*)d_ws;                     // ~17.8 MB used

    prep_kernel<<<BN + CN, 256, 0, stream>>>(inp, w_dist, attn, ws);
    dim3 gA(BN / TM, CN / TN, NZ);                 // 8 x 8 x 8 = 512 blocks
    dist_kernel<<<gA, 256, 0, stream>>>(ws, w_dist, ws);
    finish_kernel<<<BN / 4, 256, 0, stream>>>(ws, mask, w_assoc, out);
}